// Round 5
// baseline (667.884 us; speedup 1.0000x reference)
//
#include <hip/hip_runtime.h>
#include <hip/hip_bf16.h>

#define N_NODES 100000
#define N_EDGES 1600000
#define DIM 128
#define NHEAD 8
#define HDIM 16
#define NB 1563  // ceil(N_NODES/64) buckets for the two-phase edge sort

typedef __attribute__((ext_vector_type(8))) short short8;
typedef __attribute__((ext_vector_type(4))) float f32x4;

__device__ __forceinline__ unsigned short f2bf(float f) {
  union { __hip_bfloat16 h; unsigned short u; } c;
  c.h = __float2bfloat16(f);
  return c.u;
}

// Convert the three 128x128 weight matrices in one launch.
__global__ __launch_bounds__(256) void cvt3_kernel(const float* __restrict__ a,
                                                   const float* __restrict__ b,
                                                   const float* __restrict__ c,
                                                   unsigned short* __restrict__ y) {
  int i = blockIdx.x * 256 + threadIdx.x;  // 0..12287
  const float* src = (i < 4096) ? a : ((i < 8192) ? b : c);
  int j = (i < 4096) ? i : ((i < 8192) ? i - 4096 : i - 8192);
  float4 v = ((const float4*)src)[j];
  ushort4 o;
  o.x = f2bf(v.x); o.y = f2bf(v.y); o.z = f2bf(v.z); o.w = f2bf(v.w);
  ((ushort4*)y)[i] = o;
}

// ---------------- CSR construction ----------------

__global__ __launch_bounds__(256) void hist_kernel(const int* __restrict__ dst,
                                                   int* __restrict__ cnt) {
  int e = blockIdx.x * 256 + threadIdx.x;
  if (e < N_EDGES) atomicAdd(&cnt[dst[e]], 1);
}

__global__ __launch_bounds__(256) void scan1_kernel(const int* __restrict__ cnt,
                                                    int* __restrict__ rowptr,
                                                    int* __restrict__ partials) {
  __shared__ int sums[256];
  int t = threadIdx.x;
  int base = blockIdx.x * 1024 + t * 4;
  int v[4];
  int tot = 0;
#pragma unroll
  for (int j = 0; j < 4; j++) {
    int idx = base + j;
    v[j] = (idx < N_NODES) ? cnt[idx] : 0;
    tot += v[j];
  }
  sums[t] = tot;
  __syncthreads();
  for (int off = 1; off < 256; off <<= 1) {
    int x = (t >= off) ? sums[t - off] : 0;
    __syncthreads();
    sums[t] += x;
    __syncthreads();
  }
  if (t == 255) partials[blockIdx.x] = sums[255];
  int run = (t == 0) ? 0 : sums[t - 1];
#pragma unroll
  for (int j = 0; j < 4; j++) {
    int idx = base + j;
    if (idx < N_NODES) rowptr[idx] = run;
    run += v[j];
  }
}

__global__ __launch_bounds__(128) void scan2_kernel(int* partials, int np) {
  __shared__ int s[128];
  int t = threadIdx.x;
  s[t] = (t < np) ? partials[t] : 0;
  __syncthreads();
  for (int off = 1; off < 128; off <<= 1) {
    int x = (t >= off) ? s[t - off] : 0;
    __syncthreads();
    s[t] += x;
    __syncthreads();
  }
  int excl = (t == 0) ? 0 : s[t - 1];
  if (t < np) partials[t] = excl;
}

// Finalize rowptr; seed per-bucket frontier bnxt[b] = rowptr[b*64].
__global__ __launch_bounds__(256) void scan3_kernel(int* __restrict__ rowptr,
                                                    int* __restrict__ bnxt,
                                                    const int* __restrict__ partials) {
  int i = blockIdx.x * 256 + threadIdx.x;
  if (i < N_NODES) {
    int v = rowptr[i] + partials[i >> 10];
    rowptr[i] = v;
    if ((i & 63) == 0) bnxt[i >> 6] = v;
  }
  if (i == 0) rowptr[N_NODES] = N_EDGES;
}

// Phase A: scatter edges into their bucket's contiguous region (dense write frontiers).
// payload = (src<<6) | (dst&63): src<2^17, 6 bucket-local dst bits -> 23 bits.
__global__ __launch_bounds__(256) void bucket_scatter_kernel(const int* __restrict__ src,
                                                             const int* __restrict__ dst,
                                                             int* __restrict__ bnxt,
                                                             unsigned int* __restrict__ payload) {
  int e = blockIdx.x * 256 + threadIdx.x;
  if (e < N_EDGES) {
    int s = src[e];
    int d = dst[e];
    int pos = atomicAdd(&bnxt[d >> 6], 1);
    payload[pos] = ((unsigned int)s << 6) | (unsigned int)(d & 63);
  }
}

// Phase B: one block per bucket; LDS counters assign final CSR slots; writes land in
// the bucket's own ~4KB contiguous region -> full-line writes, no cross-XCD ping-pong.
__global__ __launch_bounds__(256) void bucket_sort_kernel(const unsigned int* __restrict__ payload,
                                                          const int* __restrict__ rowptr,
                                                          int* __restrict__ esrc) {
  __shared__ int lnxt[64];
  int b = blockIdx.x;
  int node0 = b << 6;
  int t = threadIdx.x;
  if (t < 64) {
    int nid = node0 + t;
    lnxt[t] = rowptr[(nid < N_NODES) ? nid : N_NODES];
  }
  __syncthreads();
  int beg = rowptr[node0];
  int hi = node0 + 64;
  int end = rowptr[(hi < N_NODES) ? hi : N_NODES];
  for (int i = beg + t; i < end; i += 256) {
    unsigned int p = payload[i];
    int pos = atomicAdd(&lnxt[p & 63], 1);
    esrc[pos] = (int)(p >> 6);
  }
}

// ---------------- K/V projection via bf16 MFMA (fused fp32->bf16 of A) ----------------
// KV row layout (256 shorts): slot 4p+0 = K[2p], 4p+1 = K[2p+1], 4p+2 = V[2p], 4p+3 = V[2p+1]
__global__ __launch_bounds__(256) void kv_proj_mfma(const float* __restrict__ A,
                                                    const unsigned short* __restrict__ Wk,
                                                    const float* __restrict__ bk,
                                                    const unsigned short* __restrict__ Wv,
                                                    const float* __restrict__ bv,
                                                    unsigned short* __restrict__ KV, int n) {
  int w = threadIdx.x >> 6, lane = threadIdx.x & 63;
  int m = lane & 15, quad = lane >> 4;
  int rbase = blockIdx.x * 64 + w * 16;
  int arow = rbase + m;
  if (arow >= n) arow = n - 1;
  const float* ap = A + (size_t)arow * DIM + quad * 8;
  short8 af[4];
#pragma unroll
  for (int t = 0; t < 4; t++) {
    float4 lo = *(const float4*)(ap + 32 * t);
    float4 hi = *(const float4*)(ap + 32 * t + 4);
    short8 f;
    f[0] = (short)f2bf(lo.x); f[1] = (short)f2bf(lo.y);
    f[2] = (short)f2bf(lo.z); f[3] = (short)f2bf(lo.w);
    f[4] = (short)f2bf(hi.x); f[5] = (short)f2bf(hi.y);
    f[6] = (short)f2bf(hi.z); f[7] = (short)f2bf(hi.w);
    af[t] = f;
  }
#pragma unroll
  for (int ct = 0; ct < 16; ct++) {
    const unsigned short* W = (ct < 8) ? Wk : Wv;
    const float* bias = (ct < 8) ? bk : bv;
    int c0 = (ct & 7) * 16;
    const unsigned short* wp = W + (size_t)(c0 + m) * DIM + quad * 8;
    f32x4 acc = {0.f, 0.f, 0.f, 0.f};
    acc = __builtin_amdgcn_mfma_f32_16x16x32_bf16(af[0], *(const short8*)(wp), acc, 0, 0, 0);
    acc = __builtin_amdgcn_mfma_f32_16x16x32_bf16(af[1], *(const short8*)(wp + 32), acc, 0, 0, 0);
    acc = __builtin_amdgcn_mfma_f32_16x16x32_bf16(af[2], *(const short8*)(wp + 64), acc, 0, 0, 0);
    acc = __builtin_amdgcn_mfma_f32_16x16x32_bf16(af[3], *(const short8*)(wp + 96), acc, 0, 0, 0);
    float bb = bias[c0 + m];
    int c = c0 + m;
    int slot = ((ct < 8) ? 0 : 2) + 4 * (c >> 1) + (c & 1);
#pragma unroll
    for (int r = 0; r < 4; r++) {
      int rr = rbase + quad * 4 + r;
      if (rr < n) KV[(size_t)rr * 256 + slot] = f2bf(acc[r] + bb);
    }
  }
}

// ---------------- Output projection via bf16 MFMA ----------------
__global__ __launch_bounds__(256) void o_proj_mfma(const unsigned short* __restrict__ A,
                                                   const unsigned short* __restrict__ Wo,
                                                   const float* __restrict__ bo,
                                                   float* __restrict__ out, int n) {
  int w = threadIdx.x >> 6, lane = threadIdx.x & 63;
  int m = lane & 15, quad = lane >> 4;
  int rbase = blockIdx.x * 64 + w * 16;
  int arow = rbase + m;
  if (arow >= n) arow = n - 1;
  const unsigned short* ap = A + (size_t)arow * DIM + quad * 8;
  short8 af0 = *(const short8*)(ap);
  short8 af1 = *(const short8*)(ap + 32);
  short8 af2 = *(const short8*)(ap + 64);
  short8 af3 = *(const short8*)(ap + 96);
#pragma unroll
  for (int ct = 0; ct < 8; ct++) {
    int c0 = ct * 16;
    const unsigned short* wp = Wo + (size_t)(c0 + m) * DIM + quad * 8;
    f32x4 acc = {0.f, 0.f, 0.f, 0.f};
    acc = __builtin_amdgcn_mfma_f32_16x16x32_bf16(af0, *(const short8*)(wp), acc, 0, 0, 0);
    acc = __builtin_amdgcn_mfma_f32_16x16x32_bf16(af1, *(const short8*)(wp + 32), acc, 0, 0, 0);
    acc = __builtin_amdgcn_mfma_f32_16x16x32_bf16(af2, *(const short8*)(wp + 64), acc, 0, 0, 0);
    acc = __builtin_amdgcn_mfma_f32_16x16x32_bf16(af3, *(const short8*)(wp + 96), acc, 0, 0, 0);
    float bb = bo[c0 + m];
#pragma unroll
    for (int r = 0; r < 4; r++) {
      int rr = rbase + quad * 4 + r;
      if (rr < n) out[(size_t)rr * DIM + c0 + m] = acc[r] + bb;
    }
  }
}

// ---------------- Per-dst softmax attention, unrolled x8, fused KV gather ----------------
__global__ __launch_bounds__(256) void attn_kernel(const float* __restrict__ q,
                                                   const unsigned short* __restrict__ KV,
                                                   const int* __restrict__ rowptr,
                                                   const int* __restrict__ esrc,
                                                   unsigned short* __restrict__ pre) {
  int wid = blockIdx.x * 4 + __builtin_amdgcn_readfirstlane(threadIdx.x >> 6);
  int lane = threadIdx.x & 63;
  const float SCALE = 0.25f * 1.44269504088896340736f;  // 1/sqrt(16) * log2(e)
  float2 qv = *(const float2*)(q + (size_t)wid * DIM + lane * 2);
  float qx = qv.x * SCALE, qy = qv.y * SCALE;
  const unsigned short* base = KV + lane * 4;

  float l = 0.f, o0 = 0.f, o1 = 0.f;
  int beg = rowptr[wid], end = rowptr[wid + 1];

#define EDGE(d)                                                              \
  {                                                                          \
    float k0 = __uint_as_float((d).x << 16);                                 \
    float k1 = __uint_as_float((d).x & 0xffff0000u);                         \
    float part = fmaf(k1, qy, k0 * qx);                                      \
    part += __shfl_xor(part, 1);                                             \
    part += __shfl_xor(part, 2);                                             \
    part += __shfl_xor(part, 4);                                             \
    float e = exp2f(part);                                                   \
    l += e;                                                                  \
    o0 = fmaf(e, __uint_as_float((d).y << 16), o0);                          \
    o1 = fmaf(e, __uint_as_float((d).y & 0xffff0000u), o1);                  \
  }

  int i = beg;
  for (; i + 8 <= end; i += 8) {
    int ss[8];
#pragma unroll
    for (int j = 0; j < 8; j++) ss[j] = esrc[i + j];
    uint2 d[8];
#pragma unroll
    for (int j = 0; j < 8; j++) d[j] = *(const uint2*)(base + (size_t)ss[j] * 256);
#pragma unroll
    for (int j = 0; j < 8; j++) EDGE(d[j])
  }
  if (i + 4 <= end) {
    int s0 = esrc[i + 0], s1 = esrc[i + 1], s2 = esrc[i + 2], s3 = esrc[i + 3];
    uint2 d0 = *(const uint2*)(base + (size_t)s0 * 256);
    uint2 d1 = *(const uint2*)(base + (size_t)s1 * 256);
    uint2 d2 = *(const uint2*)(base + (size_t)s2 * 256);
    uint2 d3 = *(const uint2*)(base + (size_t)s3 * 256);
    EDGE(d0) EDGE(d1) EDGE(d2) EDGE(d3)
    i += 4;
  }
  for (; i < end; ++i) {
    int s = esrc[i];
    uint2 d = *(const uint2*)(base + (size_t)s * 256);
    EDGE(d)
  }
#undef EDGE

  float inv = __builtin_amdgcn_rcpf(l + 1e-16f);
  ushort2 r;
  r.x = f2bf(o0 * inv);
  r.y = f2bf(o1 * inv);
  *(ushort2*)(pre + (size_t)wid * DIM + lane * 2) = r;
}

// ---------------- launch ----------------

extern "C" void kernel_launch(void* const* d_in, const int* in_sizes, int n_in,
                              void* d_out, int out_size, void* d_ws, size_t ws_size,
                              hipStream_t stream) {
  const float* q  = (const float*)d_in[0];
  const float* kv = (const float*)d_in[1];
  const int* ei   = (const int*)d_in[2];
  const float* Wk = (const float*)d_in[3];
  const float* bk = (const float*)d_in[4];
  const float* Wv = (const float*)d_in[5];
  const float* bv = (const float*)d_in[6];
  const float* Wo = (const float*)d_in[7];
  const float* bo = (const float*)d_in[8];
  float* out = (float*)d_out;
  const int* srcp = ei;            // edge_index[0]
  const int* dstp = ei + N_EDGES;  // edge_index[1]

  char* ws = (char*)d_ws;
  size_t o = 0;
  auto alloc = [&](size_t bytes) {
    void* p = ws + o;
    o += (bytes + 511) & ~(size_t)511;
    return p;
  };
  unsigned short* Wkb = (unsigned short*)alloc((size_t)DIM * DIM * 2);      // contiguous:
  unsigned short* Wvb = (unsigned short*)alloc((size_t)DIM * DIM * 2);      //   32768 B each
  unsigned short* Wob = (unsigned short*)alloc((size_t)DIM * DIM * 2);
  unsigned short* KV  = (unsigned short*)alloc((size_t)N_NODES * 256 * 2);  // 51.2 MB
  unsigned short* pre = (unsigned short*)alloc((size_t)N_NODES * DIM * 2);  // 25.6 MB
  int* esrc     = (int*)alloc((size_t)N_EDGES * 4);                         // 6.4 MB
  unsigned int* payload = (unsigned int*)alloc((size_t)N_EDGES * 4);        // 6.4 MB
  int* cnt      = (int*)alloc((size_t)N_NODES * 4);
  int* rowptr   = (int*)alloc((size_t)(N_NODES + 1) * 4);
  int* bnxt     = (int*)alloc((size_t)NB * 4);
  int* partials = (int*)alloc(1024);
  (void)ws_size;  // ~92 MB

  hipMemsetAsync(cnt, 0, (size_t)N_NODES * 4, stream);
  cvt3_kernel<<<48, 256, 0, stream>>>(Wk, Wv, Wo, Wkb);  // Wkb|Wvb|Wob contiguous
  // CSR build
  hist_kernel<<<(N_EDGES + 255) / 256, 256, 0, stream>>>(dstp, cnt);
  int np = (N_NODES + 1023) / 1024;  // 98
  scan1_kernel<<<np, 256, 0, stream>>>(cnt, rowptr, partials);
  scan2_kernel<<<1, 128, 0, stream>>>(partials, np);
  scan3_kernel<<<(N_NODES + 255) / 256, 256, 0, stream>>>(rowptr, bnxt, partials);
  bucket_scatter_kernel<<<(N_EDGES + 255) / 256, 256, 0, stream>>>(srcp, dstp, bnxt, payload);
  bucket_sort_kernel<<<NB, 256, 0, stream>>>(payload, rowptr, esrc);
  // projections + attention
  kv_proj_mfma<<<(N_NODES + 63) / 64, 256, 0, stream>>>(kv, Wkb, bk, Wvb, bv, KV, N_NODES);
  attn_kernel<<<N_NODES / 4, 256, 0, stream>>>(q, KV, rowptr, esrc, pre);
  o_proj_mfma<<<(N_NODES + 63) / 64, 256, 0, stream>>>(pre, Wob, bo, out, N_NODES);
}